// Round 2
// baseline (109.173 us; speedup 1.0000x reference)
//
#include <hip/hip_runtime.h>
#include <hip/hip_bf16.h>

// DistMult score: out[b] = sum_d src[b,d] * M[rel,d] * dst[b,d]
// B=500000, D=128. Memory-bound (~514 MB traffic; ~256 MB L3-resident).
//
// 32 lanes per row, one float4 per lane; wave64 covers 2 consecutive rows
// (contiguous 1 KiB per load instruction). R1 change: 4x row unroll per
// grid-stride iteration -> 8 independent dwordx4 loads in flight per wave
// before any waitcnt, and 4 independent shuffle-reduction chains that
// overlap each other's ds_swizzle latency. Fixes the latency-bound profile
// (R0: VALUBusy 5%, HBM 21%, occupancy 80% -> both-pipes-idle).

__global__ __launch_bounds__(256) void distmult_kernel(
    const float* __restrict__ src,
    const float* __restrict__ dst,
    const float* __restrict__ M,
    const int* __restrict__ rel_idx,
    float* __restrict__ out,
    int B)
{
    const int rel  = rel_idx[0];
    const int lane = threadIdx.x & 31;
    const float4 r4 = reinterpret_cast<const float4*>(M + (size_t)rel * 128)[lane];

    const int group = (int)((blockIdx.x * blockDim.x + threadIdx.x) >> 5);
    const int step  = (int)((gridDim.x * blockDim.x) >> 5);

    const float4* __restrict__ src4 = reinterpret_cast<const float4*>(src);
    const float4* __restrict__ dst4 = reinterpret_cast<const float4*>(dst);

    int row = group;

    // main loop: 4 rows per iteration, loads batched before compute
    for (; row + 3 * step < B; row += 4 * step) {
        const size_t b0 = (size_t)(row)            * 32 + lane;
        const size_t b1 = (size_t)(row +     step) * 32 + lane;
        const size_t b2 = (size_t)(row + 2 * step) * 32 + lane;
        const size_t b3 = (size_t)(row + 3 * step) * 32 + lane;

        // 8 independent 16B loads -> deep MLP per wave
        const float4 s0 = src4[b0];
        const float4 d0 = dst4[b0];
        const float4 s1 = src4[b1];
        const float4 d1 = dst4[b1];
        const float4 s2 = src4[b2];
        const float4 d2 = dst4[b2];
        const float4 s3 = src4[b3];
        const float4 d3 = dst4[b3];

        float a0 = s0.x*r4.x*d0.x + s0.y*r4.y*d0.y + s0.z*r4.z*d0.z + s0.w*r4.w*d0.w;
        float a1 = s1.x*r4.x*d1.x + s1.y*r4.y*d1.y + s1.z*r4.z*d1.z + s1.w*r4.w*d1.w;
        float a2 = s2.x*r4.x*d2.x + s2.y*r4.y*d2.y + s2.z*r4.z*d2.z + s2.w*r4.w*d2.w;
        float a3 = s3.x*r4.x*d3.x + s3.y*r4.y*d3.y + s3.z*r4.z*d3.z + s3.w*r4.w*d3.w;

        // 4 independent reduction chains, interleaved -> swizzle latency overlaps
        #pragma unroll
        for (int m = 16; m > 0; m >>= 1) {
            a0 += __shfl_xor(a0, m);
            a1 += __shfl_xor(a1, m);
            a2 += __shfl_xor(a2, m);
            a3 += __shfl_xor(a3, m);
        }

        if (lane == 0) {
            out[row]            = a0;
            out[row +     step] = a1;
            out[row + 2 * step] = a2;
            out[row + 3 * step] = a3;
        }
    }

    // remainder
    for (; row < B; row += step) {
        const size_t b = (size_t)row * 32 + lane;
        const float4 s = src4[b];
        const float4 d = dst4[b];
        float a = s.x*r4.x*d.x + s.y*r4.y*d.y + s.z*r4.z*d.z + s.w*r4.w*d.w;
        #pragma unroll
        for (int m = 16; m > 0; m >>= 1)
            a += __shfl_xor(a, m);
        if (lane == 0) out[row] = a;
    }
}

extern "C" void kernel_launch(void* const* d_in, const int* in_sizes, int n_in,
                              void* d_out, int out_size, void* d_ws, size_t ws_size,
                              hipStream_t stream)
{
    const float* src = (const float*)d_in[0];   // [B,128] f32
    const float* dst = (const float*)d_in[1];   // [B,128] f32
    const float* M   = (const float*)d_in[2];   // [1000,128] f32
    const int*   rel = (const int*)d_in[3];     // scalar (1-elem int array)
    float* out = (float*)d_out;                 // [B] f32 (shape [B,1,1])

    const int B = in_sizes[0] / 128;

    const int block = 256;
    const int grid  = 2048;   // 32 waves/CU -> max occupancy; grid-stride covers B
    distmult_kernel<<<grid, block, 0, stream>>>(src, dst, M, rel, out, B);
}

// Round 4
// 98.156 us; speedup vs baseline: 1.1122x; 1.1122x over previous
//
#include <hip/hip_runtime.h>
#include <hip/hip_bf16.h>

// DistMult score: out[b] = sum_d src[b,d] * M[rel,d] * dst[b,d]
// B=500000, D=128. Memory-bound: 512 MB reads (~half L3-resident), 2 MB write.
//
// R3 = R2 with the DPP control as a template (compile-time) constant.
//  - 16 lanes per row, each lane owns 2 consecutive float4s (32 B contiguous).
//  - Reduction = 4x DPP row_shr adds (pure VALU, no ds_swizzle / lgkmcnt).
//  - Lane 15 of each 16-lane group holds the row sum.
// R1 lesson: manual MLP unroll neutral (compiler already pipelines); keep a
// light 2x unroll only.

template <int CTRL>
__device__ __forceinline__ float dpp_shr_add(float x) {
    int xi = __builtin_bit_cast(int, x);
    // bound_ctrl=true: lanes shifting in from out-of-range read 0
    int yi = __builtin_amdgcn_update_dpp(0, xi, CTRL, 0xF, 0xF, true);
    return x + __builtin_bit_cast(float, yi);
}

__device__ __forceinline__ float reduce16(float x) {
    x = dpp_shr_add<0x111>(x);  // row_shr:1
    x = dpp_shr_add<0x112>(x);  // row_shr:2
    x = dpp_shr_add<0x114>(x);  // row_shr:4
    x = dpp_shr_add<0x118>(x);  // row_shr:8
    return x;                   // lane 15 of each 16-lane row holds the sum
}

__global__ __launch_bounds__(256) void distmult_kernel(
    const float* __restrict__ src,
    const float* __restrict__ dst,
    const float* __restrict__ M,
    const int* __restrict__ rel_idx,
    float* __restrict__ out,
    int B)
{
    const int rel    = rel_idx[0];
    const int lane16 = threadIdx.x & 15;

    // rel row: 128 floats; lane l owns float4s 2l and 2l+1 (32 B).
    const float4* __restrict__ M4 = reinterpret_cast<const float4*>(M + (size_t)rel * 128);
    const float4 ra = M4[lane16 * 2];
    const float4 rb = M4[lane16 * 2 + 1];

    const int group = (int)((blockIdx.x * blockDim.x + threadIdx.x) >> 4);
    const int step  = (int)((gridDim.x * blockDim.x) >> 4);

    const float4* __restrict__ src4 = reinterpret_cast<const float4*>(src);
    const float4* __restrict__ dst4 = reinterpret_cast<const float4*>(dst);

    int row = group;

    for (; row + step < B; row += 2 * step) {
        const size_t b0 = (size_t)(row)        * 32 + lane16 * 2;
        const size_t b1 = (size_t)(row + step) * 32 + lane16 * 2;

        const float4 s0a = src4[b0];
        const float4 s0b = src4[b0 + 1];
        const float4 d0a = dst4[b0];
        const float4 d0b = dst4[b0 + 1];
        const float4 s1a = src4[b1];
        const float4 s1b = src4[b1 + 1];
        const float4 d1a = dst4[b1];
        const float4 d1b = dst4[b1 + 1];

        float a0 = s0a.x*ra.x*d0a.x + s0a.y*ra.y*d0a.y + s0a.z*ra.z*d0a.z + s0a.w*ra.w*d0a.w
                 + s0b.x*rb.x*d0b.x + s0b.y*rb.y*d0b.y + s0b.z*rb.z*d0b.z + s0b.w*rb.w*d0b.w;
        float a1 = s1a.x*ra.x*d1a.x + s1a.y*ra.y*d1a.y + s1a.z*ra.z*d1a.z + s1a.w*ra.w*d1a.w
                 + s1b.x*rb.x*d1b.x + s1b.y*rb.y*d1b.y + s1b.z*rb.z*d1b.z + s1b.w*rb.w*d1b.w;

        a0 = reduce16(a0);
        a1 = reduce16(a1);

        if (lane16 == 15) {
            out[row]        = a0;
            out[row + step] = a1;
        }
    }

    for (; row < B; row += step) {
        const size_t b = (size_t)row * 32 + lane16 * 2;
        const float4 sa = src4[b];
        const float4 sb = src4[b + 1];
        const float4 da = dst4[b];
        const float4 db = dst4[b + 1];
        float a = sa.x*ra.x*da.x + sa.y*ra.y*da.y + sa.z*ra.z*da.z + sa.w*ra.w*da.w
                + sb.x*rb.x*db.x + sb.y*rb.y*db.y + sb.z*rb.z*db.z + sb.w*rb.w*db.w;
        a = reduce16(a);
        if (lane16 == 15) out[row] = a;
    }
}

extern "C" void kernel_launch(void* const* d_in, const int* in_sizes, int n_in,
                              void* d_out, int out_size, void* d_ws, size_t ws_size,
                              hipStream_t stream)
{
    const float* src = (const float*)d_in[0];   // [B,128] f32
    const float* dst = (const float*)d_in[1];   // [B,128] f32
    const float* M   = (const float*)d_in[2];   // [1000,128] f32
    const int*   rel = (const int*)d_in[3];     // scalar (1-elem int array)
    float* out = (float*)d_out;                 // [B] f32 (shape [B,1,1])

    const int B = in_sizes[0] / 128;

    const int block = 256;
    const int grid  = 2048;   // 32 waves/CU; grid-stride covers B
    distmult_kernel<<<grid, block, 0, stream>>>(src, dst, M, rel, out, B);
}

// Round 5
// 78.681 us; speedup vs baseline: 1.3875x; 1.2475x over previous
//
#include <hip/hip_runtime.h>
#include <hip/hip_bf16.h>

// DistMult score: out[b] = sum_d src[b,d] * M[rel,d] * dst[b,d]
// B=500000, D=128. 512 MB reads / 2 MB write per call.
//
// R4: L3 working-set partition. Both 256 MB arrays thrash the 256 MiB
// Infinity Cache (random-replacement -> ~50% hit on each, observed
// FETCH=251 MB). Mark src loads non-temporal (nt -> stream around / evict
// first in LLC) so the LLC stably holds dst only (fits exactly); src then
// streams from HBM at full rate while dst hits L3, and the paths overlap.
//
// Kept from R3: 16 lanes/row, 2 float4/lane, DPP row_shr reduction (pure
// VALU, no LDS pipe), light 2x unroll. R1 lesson: deeper unroll neutral.

typedef float f32x4 __attribute__((ext_vector_type(4)));

template <int CTRL>
__device__ __forceinline__ float dpp_shr_add(float x) {
    int xi = __builtin_bit_cast(int, x);
    int yi = __builtin_amdgcn_update_dpp(0, xi, CTRL, 0xF, 0xF, true);
    return x + __builtin_bit_cast(float, yi);
}

__device__ __forceinline__ float reduce16(float x) {
    x = dpp_shr_add<0x111>(x);  // row_shr:1
    x = dpp_shr_add<0x112>(x);  // row_shr:2
    x = dpp_shr_add<0x114>(x);  // row_shr:4
    x = dpp_shr_add<0x118>(x);  // row_shr:8
    return x;                   // lane 15 of each 16-lane row holds the sum
}

__device__ __forceinline__ float dot3(f32x4 s, f32x4 r, f32x4 d) {
    return s.x*r.x*d.x + s.y*r.y*d.y + s.z*r.z*d.z + s.w*r.w*d.w;
}

__global__ __launch_bounds__(256) void distmult_kernel(
    const float* __restrict__ src,
    const float* __restrict__ dst,
    const float* __restrict__ M,
    const int* __restrict__ rel_idx,
    float* __restrict__ out,
    int B)
{
    const int rel    = rel_idx[0];
    const int lane16 = threadIdx.x & 15;

    const f32x4* __restrict__ M4 = reinterpret_cast<const f32x4*>(M + (size_t)rel * 128);
    const f32x4 ra = M4[lane16 * 2];
    const f32x4 rb = M4[lane16 * 2 + 1];

    const int group = (int)((blockIdx.x * blockDim.x + threadIdx.x) >> 4);
    const int step  = (int)((gridDim.x * blockDim.x) >> 4);

    const f32x4* __restrict__ src4 = reinterpret_cast<const f32x4*>(src);
    const f32x4* __restrict__ dst4 = reinterpret_cast<const f32x4*>(dst);

    int row = group;

    for (; row + step < B; row += 2 * step) {
        const size_t b0 = (size_t)(row)        * 32 + lane16 * 2;
        const size_t b1 = (size_t)(row + step) * 32 + lane16 * 2;

        // src: non-temporal (bypass/evict-first in LLC) -> LLC keeps dst only
        const f32x4 s0a = __builtin_nontemporal_load(src4 + b0);
        const f32x4 s0b = __builtin_nontemporal_load(src4 + b0 + 1);
        const f32x4 d0a = dst4[b0];
        const f32x4 d0b = dst4[b0 + 1];
        const f32x4 s1a = __builtin_nontemporal_load(src4 + b1);
        const f32x4 s1b = __builtin_nontemporal_load(src4 + b1 + 1);
        const f32x4 d1a = dst4[b1];
        const f32x4 d1b = dst4[b1 + 1];

        float a0 = dot3(s0a, ra, d0a) + dot3(s0b, rb, d0b);
        float a1 = dot3(s1a, ra, d1a) + dot3(s1b, rb, d1b);

        a0 = reduce16(a0);
        a1 = reduce16(a1);

        if (lane16 == 15) {
            out[row]        = a0;
            out[row + step] = a1;
        }
    }

    for (; row < B; row += step) {
        const size_t b = (size_t)row * 32 + lane16 * 2;
        const f32x4 sa = __builtin_nontemporal_load(src4 + b);
        const f32x4 sb = __builtin_nontemporal_load(src4 + b + 1);
        const f32x4 da = dst4[b];
        const f32x4 db = dst4[b + 1];
        float a = dot3(sa, ra, da) + dot3(sb, rb, db);
        a = reduce16(a);
        if (lane16 == 15) out[row] = a;
    }
}

extern "C" void kernel_launch(void* const* d_in, const int* in_sizes, int n_in,
                              void* d_out, int out_size, void* d_ws, size_t ws_size,
                              hipStream_t stream)
{
    const float* src = (const float*)d_in[0];   // [B,128] f32
    const float* dst = (const float*)d_in[1];   // [B,128] f32
    const float* M   = (const float*)d_in[2];   // [1000,128] f32
    const int*   rel = (const int*)d_in[3];     // scalar (1-elem int array)
    float* out = (float*)d_out;                 // [B] f32 (shape [B,1,1])

    const int B = in_sizes[0] / 128;

    const int block = 256;
    const int grid  = 2048;   // 32 waves/CU; grid-stride covers B
    distmult_kernel<<<grid, block, 0, stream>>>(src, dst, M, rel, out, B);
}